// Round 7
// baseline (193.781 us; speedup 1.0000x reference)
//
#include <hip/hip_runtime.h>
#include <hip/hip_bf16.h>

#define B_    8
#define N_    1024
#define DIM_  512
#define H_    8
#define DH_   64
#define SCALE_ 0.125f

typedef unsigned short u16;
typedef __attribute__((ext_vector_type(8))) short bf16x8;
typedef __attribute__((ext_vector_type(4))) float f32x4;
typedef __attribute__((ext_vector_type(4))) _Float16 h16x4;

__device__ __forceinline__ u16 f2bf(float f) {
  union { float f; unsigned u; } v; v.f = f;
  return (u16)((v.u + 0x7fffu + ((v.u >> 16) & 1u)) >> 16);
}
__device__ __forceinline__ unsigned pack2(float a, float b) {
  return (unsigned)f2bf(a) | ((unsigned)f2bf(b) << 16);
}
__device__ __forceinline__ void cp16(const void* g, void* l) {
  __builtin_amdgcn_global_load_lds(
      (const __attribute__((address_space(1))) unsigned*)g,
      (__attribute__((address_space(3))) unsigned*)l, 16, 0, 0);
}

// -------- Kernel 0: convert X/Wq/Wp -> bf16, EB = exp(rpe) -> fp16 ----------
__global__ __launch_bounds__(256) void convert_kernel(
    const float* __restrict__ X, const float* __restrict__ Wq,
    const float* __restrict__ Wp, const float* __restrict__ Bias,
    u16* __restrict__ Xb, u16* __restrict__ Wqb, u16* __restrict__ Wpb,
    _Float16* __restrict__ EB) {
  const int NX4 = (B_ * N_ * DIM_) / 4;        // 1048576
  const int NQ4 = (3 * DIM_ * DIM_) / 4;       // 196608
  const int NP4 = (DIM_ * DIM_) / 4;           // 65536
  const int i = blockIdx.x * 256 + threadIdx.x;   // total 3407872 = 13312*256
  if (i < NX4 + NQ4 + NP4) {
    const float* s; u16* d; int off;
    if (i < NX4)            { s = X;  d = Xb;  off = i; }
    else if (i < NX4 + NQ4) { s = Wq; d = Wqb; off = i - NX4; }
    else                    { s = Wp; d = Wpb; off = i - NX4 - NQ4; }
    float4 f = *(const float4*)(s + (size_t)off * 4);
    uint2 u; u.x = pack2(f.x, f.y); u.y = pack2(f.z, f.w);
    *(uint2*)(d + (size_t)off * 4) = u;
  } else {
    const int off = i - NX4 - NQ4 - NP4;
    float4 f = *(const float4*)(Bias + (size_t)off * 4);
    h16x4 o;
    o[0] = (_Float16)__expf(f.x); o[1] = (_Float16)__expf(f.y);
    o[2] = (_Float16)__expf(f.z); o[3] = (_Float16)__expf(f.w);
    *(h16x4*)(EB + (size_t)off * 4) = o;
  }
}

// ---------------- Kernel 1: QKV GEMM 128x128 tile (scale folded in Q) -------
__global__ __launch_bounds__(256) void qkv_gemm(
    const u16* __restrict__ Ab, const u16* __restrict__ Bb,
    u16* __restrict__ Q, u16* __restrict__ K, u16* __restrict__ Vt) {
  __shared__ __align__(16) u16 smem[128 * 136];   // main: sA/sB; epi: transpose
  u16* sA = smem;
  u16* sB = smem + 128 * 64;
  const int t = threadIdx.x;
  const int wv = t >> 6, lane = t & 63, quad = (lane >> 4) & 3, l15 = lane & 15;
  const int wr = wv >> 1, wc = wv & 1;
  const int m0 = blockIdx.y * 128;
  const int n0 = blockIdx.x * 128;

  const int srow = lane >> 3;
  const int schunk = (lane & 7) ^ srow;
  const size_t ga = (size_t)(m0 + srow) * DIM_ + schunk * 8;
  const size_t gb = (size_t)(n0 + srow) * DIM_ + schunk * 8;

  f32x4 zero = {0.f, 0.f, 0.f, 0.f};
  f32x4 acc[4][4];
#pragma unroll
  for (int i = 0; i < 4; i++)
#pragma unroll
    for (int j = 0; j < 4; j++) acc[i][j] = zero;

  for (int k0 = 0; k0 < DIM_; k0 += 64) {
    __syncthreads();
#pragma unroll
    for (int i = 0; i < 4; i++) {
      const int rb = 32 * wv + 8 * i;
      cp16(Ab + ga + (size_t)rb * DIM_ + k0, &sA[rb * 64]);
      cp16(Bb + gb + (size_t)rb * DIM_ + k0, &sB[rb * 64]);
    }
    __syncthreads();
#pragma unroll
    for (int ks = 0; ks < 2; ks++) {
      bf16x8 af[4], bfv[4];
#pragma unroll
      for (int i = 0; i < 4; i++)
        af[i] = *(const bf16x8*)&sA[(wr * 64 + 16 * i + l15) * 64 +
                                    (((ks << 2) | quad) ^ (l15 & 7)) * 8];
#pragma unroll
      for (int j = 0; j < 4; j++)
        bfv[j] = *(const bf16x8*)&sB[(wc * 64 + 16 * j + l15) * 64 +
                                     (((ks << 2) | quad) ^ (l15 & 7)) * 8];
#pragma unroll
      for (int i = 0; i < 4; i++)
#pragma unroll
        for (int j = 0; j < 4; j++)
          acc[i][j] = __builtin_amdgcn_mfma_f32_16x16x32_bf16(af[i], bfv[j], acc[i][j], 0, 0, 0);
    }
  }

  const int tsel = n0 >> 9;   // 0=Q,1=K,2=V
  __syncthreads();
  if (tsel == 2) {
    // transpose C -> smem[j][m], then coalesced Vt row stores
#pragma unroll
    for (int j = 0; j < 4; j++)
#pragma unroll
      for (int i = 0; i < 4; i++) {
        ushort4 v4;
        v4.x = f2bf(acc[i][j][0]); v4.y = f2bf(acc[i][j][1]);
        v4.z = f2bf(acc[i][j][2]); v4.w = f2bf(acc[i][j][3]);
        *(ushort4*)&smem[(wc * 64 + 16 * j + l15) * 136 + wr * 64 + 16 * i + quad * 4] = v4;
      }
    __syncthreads();
    const int jr = t >> 4, ch = t & 15;
    const int b = m0 >> 10, nb = (m0 & 1023) + ch * 8;
#pragma unroll
    for (int rr = 0; rr < 8; rr++) {
      const int row = rr * 16 + jr;
      const int jg = n0 + row;
      const int h = (jg >> 6) & 7, d = jg & 63;
      uint4 v = *(const uint4*)&smem[row * 136 + ch * 8];
      *(uint4*)&Vt[(((size_t)(b * H_ + h)) * DH_ + d) * N_ + nb] = v;
    }
  } else {
    const float qs = (tsel == 0) ? SCALE_ : 1.f;   // fold softmax scale into Q
#pragma unroll
    for (int j = 0; j < 4; j++)
#pragma unroll
      for (int i = 0; i < 4; i++)
#pragma unroll
        for (int rr = 0; rr < 4; rr++)
          smem[(wr * 64 + 16 * i + quad * 4 + rr) * 136 + wc * 64 + 16 * j + l15] =
              f2bf(acc[i][j][rr] * qs);
    __syncthreads();
    const int row = t & 127, half = t >> 7;
    const int m = m0 + row;
    const int b = m >> 10, n = m & 1023;
    const int jg0 = n0 + half * 64;
    const int h = (jg0 >> 6) & 7;
    u16* dst = (tsel == 0 ? Q : K) + (((size_t)(b * H_ + h)) * N_ + n) * DH_;
    const u16* srw = &smem[row * 136 + half * 64];
#pragma unroll
    for (int cc = 0; cc < 8; cc++)
      *(uint4*)&dst[cc * 8] = *(const uint4*)&srw[cc * 8];
  }
}

// -- Kernel 2: flash attn, 32 q/wave (2 groups), 2-wave blocks, EB flat-exp --
__global__ __launch_bounds__(128) void attn_kernel(
    const u16* __restrict__ Q, const u16* __restrict__ K,
    const u16* __restrict__ Vt, const _Float16* __restrict__ EB,
    u16* __restrict__ AO) {
  __shared__ __align__(16) u16 sQ[64 * 64];
  __shared__ __align__(16) u16 sK[64 * 64];
  __shared__ __align__(16) u16 sV[64 * 64];
  __shared__ __align__(16) u16 sP[64 * 64];
  const int t = threadIdx.x;
  const int wv = t >> 6, lane = t & 63, quad = (lane >> 4) & 3, l15 = lane & 15;
  const int n0 = blockIdx.x << 6;
  const int bh = blockIdx.y, b = bh >> 3, h = bh & 7;
  // staging: 128 threads cover 64 rows x 128 B; r = row, half = 64B half
  const int r = t >> 1, half = t & 1, r7 = r & 7;
  const int sl0 = ((((half << 2) | 0) ^ r7) << 3);
  const int sl1 = ((((half << 2) | 1) ^ r7) << 3);
  const int sl2 = ((((half << 2) | 2) ^ r7) << 3);
  const int sl3 = ((((half << 2) | 3) ^ r7) << 3);

  const u16* Qb = Q + ((size_t)bh << 10) * DH_;
  const u16* Kb = K + ((size_t)bh << 10) * DH_;
  const u16* Vb = Vt + ((size_t)bh << 6) * N_;

  { // stage Q once (swizzled): rows n0..n0+63
    const u16* qs = Qb + (size_t)(n0 + r) * DH_ + half * 32;
    *(uint4*)&sQ[r * 64 + sl0] = *(const uint4*)(qs + 0);
    *(uint4*)&sQ[r * 64 + sl1] = *(const uint4*)(qs + 8);
    *(uint4*)&sQ[r * 64 + sl2] = *(const uint4*)(qs + 16);
    *(uint4*)&sQ[r * 64 + sl3] = *(const uint4*)(qs + 24);
  }
  // prefetch K/V tile 0 into registers
  uint4 kr0, kr1, kr2, kr3, vr0, vr1, vr2, vr3;
  {
    const u16* ks = Kb + (size_t)r * DH_ + half * 32;
    kr0 = *(const uint4*)(ks + 0);  kr1 = *(const uint4*)(ks + 8);
    kr2 = *(const uint4*)(ks + 16); kr3 = *(const uint4*)(ks + 24);
    const u16* vs = Vb + (size_t)r * N_ + half * 32;
    vr0 = *(const uint4*)(vs + 0);  vr1 = *(const uint4*)(vs + 8);
    vr2 = *(const uint4*)(vs + 16); vr3 = *(const uint4*)(vs + 24);
  }

  const int qrow = n0 + 32 * wv + l15;
  const _Float16* ebp0 = EB + ((size_t)h * N_ + qrow) * N_ + (quad << 2);
  const _Float16* ebp1 = ebp0 + (size_t)16 * N_;
  h16x4 ebc[2][4], ebn[2][4];
#pragma unroll
  for (int cb = 0; cb < 4; cb++) {
    ebc[0][cb] = *(const h16x4*)(ebp0 + 16 * cb);
    ebc[1][cb] = *(const h16x4*)(ebp1 + 16 * cb);
  }

  f32x4 zero = {0.f, 0.f, 0.f, 0.f};
  f32x4 O[2][4];
#pragma unroll
  for (int g = 0; g < 2; g++)
#pragma unroll
    for (int db = 0; db < 4; db++) O[g][db] = zero;
  float lsum[2] = {0.f, 0.f};

  for (int kt = 0; kt < 16; kt++) {
    __syncthreads();   // all waves done reading previous tile
    *(uint4*)&sK[r * 64 + sl0] = kr0; *(uint4*)&sK[r * 64 + sl1] = kr1;
    *(uint4*)&sK[r * 64 + sl2] = kr2; *(uint4*)&sK[r * 64 + sl3] = kr3;
    *(uint4*)&sV[r * 64 + sl0] = vr0; *(uint4*)&sV[r * 64 + sl1] = vr1;
    *(uint4*)&sV[r * 64 + sl2] = vr2; *(uint4*)&sV[r * 64 + sl3] = vr3;
    if (kt < 15) {   // issue next tile's global loads; fly during compute
      const int m1 = (kt + 1) << 6;
      const u16* ks = Kb + (size_t)(m1 + r) * DH_ + half * 32;
      kr0 = *(const uint4*)(ks + 0);  kr1 = *(const uint4*)(ks + 8);
      kr2 = *(const uint4*)(ks + 16); kr3 = *(const uint4*)(ks + 24);
      const u16* vs = Vb + (size_t)r * N_ + m1 + half * 32;
      vr0 = *(const uint4*)(vs + 0);  vr1 = *(const uint4*)(vs + 8);
      vr2 = *(const uint4*)(vs + 16); vr3 = *(const uint4*)(vs + 24);
    }
    const int mn = (kt < 15) ? ((kt + 1) << 6) : 0;
#pragma unroll
    for (int cb = 0; cb < 4; cb++) {
      ebn[0][cb] = *(const h16x4*)(ebp0 + mn + 16 * cb);
      ebn[1][cb] = *(const h16x4*)(ebp1 + mn + 16 * cb);
    }
    __syncthreads();   // staged K/V visible

    // S^T[key][q] = K . Q^T  (scale pre-folded into Q); 2 q-groups
    f32x4 S[2][4];
#pragma unroll
    for (int g = 0; g < 2; g++)
#pragma unroll
      for (int cb = 0; cb < 4; cb++) S[g][cb] = zero;
#pragma unroll
    for (int ks = 0; ks < 2; ks++) {
      const int so = ((((ks << 2) | quad) ^ (l15 & 7)) << 3);
      bf16x8 qf0 = *(const bf16x8*)&sQ[(32 * wv + l15) * 64 + so];
      bf16x8 qf1 = *(const bf16x8*)&sQ[(32 * wv + 16 + l15) * 64 + so];
#pragma unroll
      for (int cb = 0; cb < 4; cb++) {
        bf16x8 kf = *(const bf16x8*)&sK[(16 * cb + l15) * 64 + so];
        S[0][cb] = __builtin_amdgcn_mfma_f32_16x16x32_bf16(kf, qf0, S[0][cb], 0, 0, 0);
        S[1][cb] = __builtin_amdgcn_mfma_f32_16x16x32_bf16(kf, qf1, S[1][cb], 0, 0, 0);
      }
    }

    // p = exp(S) * EB  (flat softmax), pack P^T into wave-local sP rows
#pragma unroll
    for (int g = 0; g < 2; g++)
#pragma unroll
      for (int cb = 0; cb < 4; cb++) {
        const float p0 = __expf(S[g][cb][0]) * (float)ebc[g][cb][0];
        const float p1 = __expf(S[g][cb][1]) * (float)ebc[g][cb][1];
        const float p2 = __expf(S[g][cb][2]) * (float)ebc[g][cb][2];
        const float p3 = __expf(S[g][cb][3]) * (float)ebc[g][cb][3];
        lsum[g] += (p0 + p1) + (p2 + p3);
        uint2 pk; pk.x = pack2(p0, p1); pk.y = pack2(p2, p3);
        *(uint2*)&sP[(32 * wv + 16 * g + l15) * 64 +
                     ((((cb << 1) | (quad >> 1)) ^ (l15 & 7)) << 3) + ((quad & 1) << 2)] = pk;
      }
    asm volatile("s_waitcnt lgkmcnt(0)" ::: "memory");   // wave-local sP fence

    // O^T[d][q] += V^T . P^T
#pragma unroll
    for (int ks = 0; ks < 2; ks++) {
      const int so = ((((ks << 2) | quad) ^ (l15 & 7)) << 3);
      bf16x8 pf0 = *(const bf16x8*)&sP[(32 * wv + l15) * 64 + so];
      bf16x8 pf1 = *(const bf16x8*)&sP[(32 * wv + 16 + l15) * 64 + so];
#pragma unroll
      for (int db = 0; db < 4; db++) {
        bf16x8 vf = *(const bf16x8*)&sV[(16 * db + l15) * 64 + so];
        O[0][db] = __builtin_amdgcn_mfma_f32_16x16x32_bf16(vf, pf0, O[0][db], 0, 0, 0);
        O[1][db] = __builtin_amdgcn_mfma_f32_16x16x32_bf16(vf, pf1, O[1][db], 0, 0, 0);
      }
    }
#pragma unroll
    for (int g = 0; g < 2; g++)
#pragma unroll
      for (int cb = 0; cb < 4; cb++) ebc[g][cb] = ebn[g][cb];
  }

#pragma unroll
  for (int g = 0; g < 2; g++) {
    float l = lsum[g];
    l += __shfl_xor(l, 16);
    l += __shfl_xor(l, 32);
    const float inv = 1.f / l;
    const int qg = n0 + 32 * wv + 16 * g + l15;
#pragma unroll
    for (int db = 0; db < 4; db++) {
      ushort4 o4;
      o4.x = f2bf(O[g][db][0] * inv); o4.y = f2bf(O[g][db][1] * inv);
      o4.z = f2bf(O[g][db][2] * inv); o4.w = f2bf(O[g][db][3] * inv);
      *(ushort4*)&AO[(((size_t)b << 10) + qg) * DIM_ + h * DH_ + 16 * db + (quad << 2)] = o4;
    }
  }
}

// ---------------- Kernel 3: output projection 128x128 tile ------------------
__global__ __launch_bounds__(256) void proj_gemm(
    const u16* __restrict__ Ab, const u16* __restrict__ Bb,
    const float* __restrict__ Pb, float* __restrict__ Out) {
  __shared__ __align__(16) u16 sA[128 * 64];
  __shared__ __align__(16) u16 sB[128 * 64];
  const int t = threadIdx.x;
  const int wv = t >> 6, lane = t & 63, quad = (lane >> 4) & 3, l15 = lane & 15;
  const int wr = wv >> 1, wc = wv & 1;
  const int m0 = blockIdx.y * 128;
  const int n0 = blockIdx.x * 128;

  const int srow = lane >> 3;
  const int schunk = (lane & 7) ^ srow;
  const size_t ga = (size_t)(m0 + srow) * DIM_ + schunk * 8;
  const size_t gb = (size_t)(n0 + srow) * DIM_ + schunk * 8;

  f32x4 zero = {0.f, 0.f, 0.f, 0.f};
  f32x4 acc[4][4];
#pragma unroll
  for (int i = 0; i < 4; i++)
#pragma unroll
    for (int j = 0; j < 4; j++) acc[i][j] = zero;

  for (int k0 = 0; k0 < DIM_; k0 += 64) {
    __syncthreads();
#pragma unroll
    for (int i = 0; i < 4; i++) {
      const int rb = 32 * wv + 8 * i;
      cp16(Ab + ga + (size_t)rb * DIM_ + k0, &sA[rb * 64]);
      cp16(Bb + gb + (size_t)rb * DIM_ + k0, &sB[rb * 64]);
    }
    __syncthreads();
#pragma unroll
    for (int ks = 0; ks < 2; ks++) {
      bf16x8 af[4], bfv[4];
#pragma unroll
      for (int i = 0; i < 4; i++)
        af[i] = *(const bf16x8*)&sA[(wr * 64 + 16 * i + l15) * 64 +
                                    (((ks << 2) | quad) ^ (l15 & 7)) * 8];
#pragma unroll
      for (int j = 0; j < 4; j++)
        bfv[j] = *(const bf16x8*)&sB[(wc * 64 + 16 * j + l15) * 64 +
                                     (((ks << 2) | quad) ^ (l15 & 7)) * 8];
#pragma unroll
      for (int i = 0; i < 4; i++)
#pragma unroll
        for (int j = 0; j < 4; j++)
          acc[i][j] = __builtin_amdgcn_mfma_f32_16x16x32_bf16(af[i], bfv[j], acc[i][j], 0, 0, 0);
    }
  }

#pragma unroll
  for (int j = 0; j < 4; j++) {
    const int jg = n0 + wc * 64 + 16 * j + l15;
    const float pb = Pb[jg];
#pragma unroll
    for (int i = 0; i < 4; i++) {
      const int mbase = m0 + wr * 64 + 16 * i + quad * 4;
#pragma unroll
      for (int rr = 0; rr < 4; rr++)
        Out[(size_t)(mbase + rr) * DIM_ + jg] = acc[i][j][rr] + pb;
    }
  }
}

extern "C" void kernel_launch(void* const* d_in, const int* in_sizes, int n_in,
                              void* d_out, int out_size, void* d_ws, size_t ws_size,
                              hipStream_t stream) {
  const float* x      = (const float*)d_in[0];
  const float* rpe    = (const float*)d_in[1];
  const float* qkv_w  = (const float*)d_in[2];
  const float* proj_w = (const float*)d_in[3];
  const float* proj_b = (const float*)d_in[4];
  float* out = (float*)d_out;

  const size_t perbuf = (size_t)B_ * N_ * DIM_;   // 4,194,304 elems
  u16* Xb  = (u16*)d_ws;                          // aliased with AO
  u16* Q   = Xb + perbuf;
  u16* K   = Q + perbuf;
  u16* Vt  = K + perbuf;
  u16* Wqb = Vt + perbuf;
  u16* Wpb = Wqb + (size_t)3 * DIM_ * DIM_;
  _Float16* EB = (_Float16*)(Wpb + (size_t)DIM_ * DIM_);  // 16.8 MB fp16
  u16* AO  = Xb;   // lifetimes disjoint

  convert_kernel<<<13312, 256, 0, stream>>>(x, qkv_w, proj_w, rpe, Xb, Wqb, Wpb, EB);
  qkv_gemm<<<dim3(12, 64), 256, 0, stream>>>(Xb, Wqb, Q, K, Vt);
  attn_kernel<<<dim3(16, 64), 128, 0, stream>>>(Q, K, Vt, EB, AO);
  proj_gemm<<<dim3(4, 64), 256, 0, stream>>>(AO, Wpb, proj_b, out);
}